// Round 2
// baseline (353.727 us; speedup 1.0000x reference)
//
#include <hip/hip_runtime.h>

// out[b,n] = sum_e c[b,n,e] * s[b,e];  B=32, N=8192, E=256, fp32.
// R1 lesson: one-shot waves (262K waves, 1 load each) were churn-bound at
// 0.8 TB/s while the harness's own fills hit 6.7 TB/s. Fix: persistent-style
// grid (2048 blocks = 8/CU), each wave owns 32 contiguous rows, unroll x4 for
// MLP. s-row loaded once per wave (chunks don't cross batch: 32 | 8192).

constexpr int kLogN       = 13;   // N = 8192 rows per batch
constexpr int kF4PerRow   = 64;   // E/4
constexpr int kRowsPerWave = 32;
constexpr int kUnroll      = 4;

__global__ __launch_bounds__(256) void ctx_seg_score_kernel(
    const float* __restrict__ c,   // [B*N, E]
    const float* __restrict__ s,   // [B, E]
    float* __restrict__ out,       // [B*N]
    int total_rows)                // B*N = 262144
{
    const int tid  = blockIdx.x * blockDim.x + threadIdx.x;
    const int wave = tid >> 6;
    const int lane = tid & 63;

    const int row0 = wave * kRowsPerWave;
    if (row0 >= total_rows) return;

    const int b = row0 >> kLogN;   // constant over this wave's chunk

    const float4* __restrict__ c4p = reinterpret_cast<const float4*>(c);
    const float4  s4 = reinterpret_cast<const float4*>(s)[(size_t)b * kF4PerRow + lane];

    #pragma unroll 2
    for (int i = 0; i < kRowsPerWave; i += kUnroll) {
        const int r = row0 + i;

        // 4 independent 1-KiB wave loads in flight (coalesced dwordx4)
        float4 a[kUnroll];
        #pragma unroll
        for (int u = 0; u < kUnroll; ++u)
            a[u] = c4p[(size_t)(r + u) * kF4PerRow + lane];

        // per-lane partial dot for each of the 4 rows, packed in a float4
        float4 p;
        p.x = fmaf(a[0].x, s4.x, fmaf(a[0].y, s4.y, fmaf(a[0].z, s4.z, a[0].w * s4.w)));
        p.y = fmaf(a[1].x, s4.x, fmaf(a[1].y, s4.y, fmaf(a[1].z, s4.z, a[1].w * s4.w)));
        p.z = fmaf(a[2].x, s4.x, fmaf(a[2].y, s4.y, fmaf(a[2].z, s4.z, a[2].w * s4.w)));
        p.w = fmaf(a[3].x, s4.x, fmaf(a[3].y, s4.y, fmaf(a[3].z, s4.z, a[3].w * s4.w)));

        // 64-lane packed butterfly reduction (4 outputs at once)
        #pragma unroll
        for (int off = 32; off > 0; off >>= 1) {
            p.x += __shfl_xor(p.x, off, 64);
            p.y += __shfl_xor(p.y, off, 64);
            p.z += __shfl_xor(p.z, off, 64);
            p.w += __shfl_xor(p.w, off, 64);
        }

        if (lane == 0)
            reinterpret_cast<float4*>(out)[r >> 2] = p;  // r is a multiple of 4
    }
}

extern "C" void kernel_launch(void* const* d_in, const int* in_sizes, int n_in,
                              void* d_out, int out_size, void* d_ws, size_t ws_size,
                              hipStream_t stream) {
    const float* c = (const float*)d_in[0];
    const float* s = (const float*)d_in[1];
    float* out = (float*)d_out;

    const int total_rows = out_size;                       // 262144
    const int waves = (total_rows + kRowsPerWave - 1) / kRowsPerWave;  // 8192
    const int threads = 256;                               // 4 waves/block
    const int blocks = (waves * 64 + threads - 1) / threads;           // 2048

    ctx_seg_score_kernel<<<blocks, threads, 0, stream>>>(c, s, out, total_rows);
}

// Round 3
// 327.560 us; speedup vs baseline: 1.0799x; 1.0799x over previous
//
#include <hip/hip_runtime.h>

// out[b,n] = sum_e c[b,n,e] * s[b,e];  B=32, N=8192, E=256, fp32.
// R2 lesson: kernel dispatch is <159us (absent from rocprof top-5); bench
// dur_us carries ~245us of harness restore/poison GPU work. Kernel itself is
// ~100us vs 43us roofline. This round: (a) grid-stride so all co-resident
// waves sweep ONE contiguous memory front per iteration (DRAM page locality),
// (b) log-merge reduction: 10 cross-lane ops per 8 rows instead of 48,
// (c) 8 independent dwordx4 in flight per wave, (d) non-temporal c loads
// (c is streamed once and re-restored by the harness every iteration).

typedef float f32x4 __attribute__((ext_vector_type(4)));

constexpr int kLogN        = 13;   // N = 8192 rows per batch
constexpr int kF4PerRow    = 64;   // E/4
constexpr int kRowsPerIter = 8;    // rows per wave per grid-stride step
constexpr int kBlocks      = 1024; // 4 blocks/CU exactly
constexpr int kThreads     = 256;  // 4 waves/block -> 4096 waves total

// Pairwise cross-lane merge: lanes with sel==0 end up owning `a`'s row,
// lanes with sel==1 own `b`'s row, each summed over the {l, l^off} pair.
__device__ __forceinline__ float lane_merge(float a, float b, int sel, int off) {
    float send = sel ? a : b;
    float recv = __shfl_xor(send, off, 64);
    return (sel ? b : a) + recv;
}

__global__ __launch_bounds__(kThreads) void ctx_seg_score_kernel(
    const float* __restrict__ c,   // [B*N, E]
    const float* __restrict__ s,   // [B, E]
    float* __restrict__ out,       // [B*N]
    int total_rows)                // B*N = 262144
{
    const int lane   = threadIdx.x & 63;
    const int gwave  = (blockIdx.x * blockDim.x + threadIdx.x) >> 6;
    const int nwaves = (gridDim.x * blockDim.x) >> 6;   // 4096

    const f32x4* __restrict__ c4p = reinterpret_cast<const f32x4*>(c);
    const float4* __restrict__ s4p = reinterpret_cast<const float4*>(s);

    const int sel1 = lane & 1;
    const int sel2 = (lane >> 1) & 1;
    const int sel4 = (lane >> 2) & 1;

    // Iteration i: waves g=0..4095 cover rows [i*32768 + 8g, ... +8) —
    // a single contiguous 32 MB front sweeping the array.
    for (int r0 = gwave * kRowsPerIter; r0 < total_rows;
         r0 += nwaves * kRowsPerIter) {

        const int b = r0 >> kLogN;            // 8 | 8192 -> same batch for all 8 rows
        const float4 s4 = s4p[b * kF4PerRow + lane];

        // 8 independent coalesced 1-KiB wave loads (non-temporal: no reuse)
        f32x4 a[kRowsPerIter];
        #pragma unroll
        for (int u = 0; u < kRowsPerIter; ++u)
            a[u] = __builtin_nontemporal_load(
                &c4p[(size_t)(r0 + u) * kF4PerRow + lane]);

        float p[kRowsPerIter];
        #pragma unroll
        for (int u = 0; u < kRowsPerIter; ++u)
            p[u] = fmaf(a[u].x, s4.x,
                   fmaf(a[u].y, s4.y,
                   fmaf(a[u].z, s4.z, a[u].w * s4.w)));

        // Merge tree: after 3 steps lane l owns row (l&7) summed over its
        // lane-octet. 7 shuffles total.
        float v01 = lane_merge(p[0], p[1], sel1, 1);
        float v23 = lane_merge(p[2], p[3], sel1, 1);
        float v45 = lane_merge(p[4], p[5], sel1, 1);
        float v67 = lane_merge(p[6], p[7], sel1, 1);
        float w03 = lane_merge(v01, v23, sel2, 2);
        float w47 = lane_merge(v45, v67, sel2, 2);
        float v   = lane_merge(w03, w47, sel4, 4);

        // Butterfly over remaining lane bits: 3 shuffles.
        v += __shfl_xor(v, 8, 64);
        v += __shfl_xor(v, 16, 64);
        v += __shfl_xor(v, 32, 64);

        // lane l (l<8) holds the total for row r0+l: 32 B coalesced store.
        if (lane < kRowsPerIter)
            out[r0 + lane] = v;
    }
}

extern "C" void kernel_launch(void* const* d_in, const int* in_sizes, int n_in,
                              void* d_out, int out_size, void* d_ws, size_t ws_size,
                              hipStream_t stream) {
    const float* c = (const float*)d_in[0];
    const float* s = (const float*)d_in[1];
    float* out = (float*)d_out;

    ctx_seg_score_kernel<<<kBlocks, kThreads, 0, stream>>>(c, s, out, out_size);
}